// Round 10
// baseline (201.774 us; speedup 1.0000x reference)
//
#include <hip/hip_runtime.h>
#include <hip/hip_bf16.h>

#define DIM 8192
#define KSPLIT 16
#define PARTIAL_ELEMS (32 * DIM)   // one fp32 copy of the output per k-chunk
#define MAGIC 0x13579BDFu          // 4 distinct bytes: never equals repeated-byte poison

typedef __bf16 bf16x8 __attribute__((ext_vector_type(8)));
typedef __bf16 bf16x2 __attribute__((ext_vector_type(2)));
typedef float f32x4 __attribute__((ext_vector_type(4)));
typedef float f32x2 __attribute__((ext_vector_type(2)));

// fp32x4 -> bf16x4 (RNE via fptrunc -> packed v_cvt_pk_bf16_f32)
__device__ __forceinline__ uint2 cvt_f4(const float4 v) {
  bf16x2 lo = __builtin_convertvector((f32x2){v.x, v.y}, bf16x2);
  bf16x2 hi = __builtin_convertvector((f32x2){v.z, v.w}, bf16x2);
  uint2 r;
  r.x = __builtin_bit_cast(unsigned, lo);
  r.y = __builtin_bit_cast(unsigned, hi);
  return r;
}

// ---------------------------------------------------------------------------
// ONE dispatch. grid 512 = 32 mc (low 5 bits) x 16 kc; block 512 (8 waves);
// 55.5 KB LDS -> 2 WG/CU -> all 512 WGs co-resident (publish-before-spin +
// full residency = deadlock-free; same residency measured working in R6).
//
// Staging + hot loop: VERBATIM the round-1 measured-passing code (70.7 us).
// Combine: STREAMING stores of partials to Ws (atomics disqualified in R6:
// ~0.3 TB/s effective), then flag-synced distributed reduction: each WG
// reduces a disjoint 32x16 output slice in fixed kc order (deterministic).
// ---------------------------------------------------------------------------
__global__ __launch_bounds__(512, 4)
void bcl_fused_kernel(const float* __restrict__ X,
                      const float* __restrict__ Blk,
                      float* __restrict__ Out,
                      float* __restrict__ Ws,
                      unsigned* __restrict__ Flag) {
  // x: [s:16][b0:2][kh:4][p:16][j:8] bf16 (32 KB): frag = contiguous 1KB
  __shared__ __align__(16) unsigned short Xl[16384];
  // blocks window: 47 slots x 512B, each repacked [qh:2][p:16][j:8]
  __shared__ __align__(16) unsigned short Wl[47 * 256];

  const int tid = threadIdx.x;
  const int mc  = blockIdx.x & 31;
  const int kc  = blockIdx.x >> 5;
  const int kbase = kc * 512;

  // ---- stage x (fp32->bf16). LDS stores linear (conflict-free).
  #pragma unroll
  for (int it = 0; it < 8; ++it) {
    const int L  = (tid + it * 512) << 2;     // elem index in Xl
    const int j4 = L & 7;
    const int p  = (L >> 3) & 15;
    const int kh = (L >> 7) & 3;
    const int b0 = (L >> 9) & 1;
    const int s  = (L >> 10) & 15;
    const int batch = b0 * 16 + p;
    const int kg = kbase + s * 32 + (kh >> 1) * 16 + (kh & 1) * 8 + j4;
    const float4 v = *reinterpret_cast<const float4*>(X + batch * DIM + kg);
    *reinterpret_cast<uint2*>(&Xl[L]) = cvt_f4(v);
  }

  // ---- stage blocks window: slot w holds blocks[(dbase+w)&511] as [qh][p][j]
  const int dbase = (mc * 16 - kc * 32 - 31) & 511;
  for (int i = tid; i < 47 * 64; i += 512) {
    const int w  = i >> 6;
    const int r  = (i & 63) << 2;             // elem in repacked block
    const int qh = r >> 7;
    const int p  = (r >> 3) & 15;
    const int j4 = r & 7;
    const int d  = (dbase + w) & 511;
    const float4 v = *reinterpret_cast<const float4*>(Blk + d * 256 + p * 16 + qh * 8 + j4);
    *reinterpret_cast<uint2*>(&Wl[w * 256 + r]) = cvt_f4(v);
  }

  __syncthreads();   // only compute barrier

  const int lane = tid & 63;
  const int wid  = tid >> 6;                  // 0..7

  // x-frag (a-operand): lane l -> Xl[s*1024 + b0*512 + l*8]
  const unsigned short* Xb = &Xl[lane << 3];
  // blocks-frag (b-operand): lanes 0-31 read slot w0, 32-63 read slot w0-1,
  // each half contiguous 512B; flat = (w0-1)*256 elems + per-lane offset:
  const unsigned short* Wb = &Wl[(((lane >> 5) ^ 1) << 8) + (((lane >> 4) & 1) << 7) + ((lane & 15) << 3)];

  f32x4 acc[2][2];
  #pragma unroll
  for (int t = 0; t < 2; ++t)
    #pragma unroll
    for (int b = 0; b < 2; ++b)
      acc[t][b] = (f32x4){0.f, 0.f, 0.f, 0.f};

  #pragma unroll 4
  for (int s = 0; s < 16; ++s) {
    const bf16x8 x0 = *reinterpret_cast<const bf16x8*>(Xb + (s << 10));
    const bf16x8 x1 = *reinterpret_cast<const bf16x8*>(Xb + (s << 10) + 512);
    #pragma unroll
    for (int t = 0; t < 2; ++t) {
      const int mt = (wid << 1) + t;          // 0..15
      const bf16x8 wf = *reinterpret_cast<const bf16x8*>(Wb + ((mt + 30 - 2 * s) << 8));
      acc[t][0] = __builtin_amdgcn_mfma_f32_16x16x32_bf16(x0, wf, acc[t][0], 0, 0, 0);
      acc[t][1] = __builtin_amdgcn_mfma_f32_16x16x32_bf16(x1, wf, acc[t][1], 0, 0, 0);
    }
  }

  // ---- partial store: C/D layout col=lane&15 (=p), row=(lane>>4)*4+reg.
  // Plain streaming stores: 4 rows x 16 contiguous cols per inst (64B segments).
  float* base = Ws + (size_t)kc * PARTIAL_ELEMS + mc * 256;
  #pragma unroll
  for (int t = 0; t < 2; ++t) {
    const int col = ((wid << 1) + t) * 16 + (lane & 15);
    #pragma unroll
    for (int b0 = 0; b0 < 2; ++b0) {
      const int brow = b0 * 16 + ((lane >> 4) << 2);
      #pragma unroll
      for (int r = 0; r < 4; ++r)
        base[(brow + r) * DIM + col] = acc[t][b0][r];
    }
  }

  // ---- publish, then wait for this mc's 16 partials
  __threadfence();                 // device scope: partials -> coherence point
  __syncthreads();                 // all threads' stores+fence precede publish
  if (tid == 0)
    __hip_atomic_store(&Flag[(mc << 4) + kc], MAGIC,
                       __ATOMIC_RELEASE, __HIP_MEMORY_SCOPE_AGENT);
  if (tid < 16) {
    while (__hip_atomic_load(&Flag[(mc << 4) + tid],
                             __ATOMIC_ACQUIRE, __HIP_MEMORY_SCOPE_AGENT) != MAGIC)
      __builtin_amdgcn_s_sleep(2);
  }
  __syncthreads();

  // ---- distributed reduction: this WG owns cols [mc*256 + kc*16, +16),
  // all 32 rows = 512 elems = 1 per thread. Fixed kc order -> deterministic.
  const int row = tid >> 4;                    // 0..31
  const int col = mc * 256 + (kc << 4) + (tid & 15);
  const float* p = Ws + row * DIM + col;
  float a = p[0];
  #pragma unroll
  for (int k = 1; k < KSPLIT; ++k) a += p[(size_t)k * PARTIAL_ELEMS];
  Out[row * DIM + col] = a;
}

extern "C" void kernel_launch(void* const* d_in, const int* in_sizes, int n_in,
                              void* d_out, int out_size, void* d_ws, size_t ws_size,
                              hipStream_t stream) {
  const float* X   = (const float*)d_in[0];   // [32, 8192] fp32
  const float* Blk = (const float*)d_in[1];   // [512, 16, 16] fp32
  float* Out = (float*)d_out;                 // [32, 8192] fp32
  unsigned* Flag = (unsigned*)d_ws;           // 512 flags (2 KB), re-poisoned each iter
  float* Ws  = (float*)((char*)d_ws + 4096);  // 16 MB fp32 partials

  bcl_fused_kernel<<<dim3(512), dim3(512), 0, stream>>>(X, Blk, Out, Ws, Flag);
}

// Round 13
// 73.666 us; speedup vs baseline: 2.7391x; 2.7391x over previous
//
#include <hip/hip_runtime.h>
#include <hip/hip_bf16.h>

#define DIM 8192

typedef __bf16 bf16x8 __attribute__((ext_vector_type(8)));
typedef __bf16 bf16x2 __attribute__((ext_vector_type(2)));
typedef float f32x4 __attribute__((ext_vector_type(4)));
typedef float f32x2 __attribute__((ext_vector_type(2)));

// fp32x4 -> bf16x4 (RNE via fptrunc -> packed v_cvt_pk_bf16_f32)
__device__ __forceinline__ uint2 cvt_f4(const float4 v) {
  bf16x2 lo = __builtin_convertvector((f32x2){v.x, v.y}, bf16x2);
  bf16x2 hi = __builtin_convertvector((f32x2){v.z, v.w}, bf16x2);
  uint2 r;
  r.x = __builtin_bit_cast(unsigned, lo);
  r.y = __builtin_bit_cast(unsigned, hi);
  return r;
}

// global->LDS direct DMA, 16B per lane. Global addr is PER-LANE (handles the
// circulant wrap); LDS base must be wave-uniform (no lane term).
#define GL2LDS(gp, lp)                                                        \
  __builtin_amdgcn_global_load_lds(                                           \
      (const __attribute__((address_space(1))) void*)(gp),                    \
      (__attribute__((address_space(3))) void*)(lp), 16, 0, 0)

// ---------------------------------------------------------------------------
// Prep: bf16 repack in EXACTLY the mono kernel's staging order.
//   Xp [b0:2][h:32][sw:8][kh:4][p:16][j:8]  bf16 (512 KB) ; per (b0,h): 8 KB
//   Wp [d:512][qh:2][p:16][j:8]             bf16 (256 KB)
// k = h*256 + sw*32 + (kh>>1)*16 + (kh&1)*8 + j ; row = b0*16 + p.
// Grid 192x256: 32768 X-chunks (8 elems) + 16384 Blk-chunks (8 elems).
// ---------------------------------------------------------------------------
__global__ __launch_bounds__(256)
void bcl_prep_kernel(const float* __restrict__ X, const float* __restrict__ Blk,
                     unsigned short* __restrict__ Xp, unsigned short* __restrict__ Wp) {
  const int T = blockIdx.x * 256 + threadIdx.x;
  if (T < 32768) {
    const int p  = T & 15;
    const int kh = (T >> 4) & 3;
    const int sw = (T >> 6) & 7;
    const int h  = (T >> 9) & 31;
    const int b0 = (T >> 14) & 1;
    const float* src = X + (b0 * 16 + p) * DIM + h * 256 + sw * 32 +
                       ((kh >> 1) << 4) + ((kh & 1) << 3);
    const float4 v0 = reinterpret_cast<const float4*>(src)[0];
    const float4 v1 = reinterpret_cast<const float4*>(src)[1];
    const uint2 a = cvt_f4(v0), b = cvt_f4(v1);
    uint4 o; o.x = a.x; o.y = a.y; o.z = b.x; o.w = b.y;
    *reinterpret_cast<uint4*>(Xp + T * 8) = o;
  } else {
    const int b  = T - 32768;
    const int d  = b >> 5;
    const int p  = b & 15;
    const int qh = (b >> 4) & 1;
    const float* src = Blk + d * 256 + p * 16 + qh * 8;
    const float4 v0 = reinterpret_cast<const float4*>(src)[0];
    const float4 v1 = reinterpret_cast<const float4*>(src)[1];
    const uint2 a = cvt_f4(v0), bb = cvt_f4(v1);
    uint4 o; o.x = a.x; o.y = a.y; o.z = bb.x; o.w = bb.y;
    *reinterpret_cast<uint4*>(Wp + b * 8) = o;
  }
}

// ---------------------------------------------------------------------------
// Mono-K kernel: grid 256 = 2 b0 x 128 col-groups; block 512 (8 waves).
// WG owns rows [b0*16,+16) x cols [cg*64,+64) over the FULL K=8192 ->
// NOTHING to combine: no Ws partials, no reduce kernel, no atomics, no flags
// (R6 measured atomics at ~0.3 TB/s; R10 measured flag+fence at ~0.2 TB/s --
// cross-XCD coherence tax disqualifies all in-kernel cross-WG combines).
// K-loop: 32 half-chunks of 256 k, double-buffered global_load_lds staging.
// Wave sw handles k-slice [sw*32,+32) of each half-chunk (verified fragment
// math, window narrowed 47->20 slots); cross-wave sum via one LDS pass at end.
// ---------------------------------------------------------------------------
__global__ __launch_bounds__(512)
void bcl_mono_kernel(const unsigned short* __restrict__ Xp,
                     const unsigned short* __restrict__ Wp,
                     float* __restrict__ Out) {
  // [0,16KB): Xl bufs (2x8KB) ; [16KB,36KB): Wl bufs (2x10KB)
  // epilogue reuses first 32KB as f32 reduce scratch.
  __shared__ __align__(16) unsigned short LDSB[18432];

  const int tid  = threadIdx.x;
  const int lane = tid & 63;
  const int wid  = tid >> 6;              // 0..7 = s-slot sw
  const int b0   = blockIdx.x & 1;
  const int cg   = blockIdx.x >> 1;       // 0..127
  const int i0   = cg << 2;               // first of 4 out col-blocks

  const char* xsrc = reinterpret_cast<const char*>(Xp) + (size_t)(b0 * 32) * 8192;
  const char* wsrc = reinterpret_cast<const char*>(Wp);
  char* Xl = reinterpret_cast<char*>(LDSB);              // + buf*8192
  char* Wl = reinterpret_cast<char*>(LDSB) + 16384;      // + buf*10240

  // stage half-chunk h into buffer buf: X 8KB (8 loads) + W 20 slots (10 loads)
  auto STAGE = [&](int h, int buf) {
    const int dbase = (i0 - (h << 4) - 15) & 511;
    for (int t = wid; t < 18; t += 8) {
      if (t < 8) {
        const int lb = t << 10;
        GL2LDS(xsrc + h * 8192 + lb + lane * 16, Xl + buf * 8192 + lb);
      } else {
        const int lb = (t - 8) << 10;
        const int B  = lb + lane * 16;
        const int w  = B >> 9;                  // slot 0..19
        const int d  = (dbase + w) & 511;
        GL2LDS(wsrc + d * 512 + (B & 511), Wl + buf * 10240 + lb);
      }
    }
  };

  f32x4 acc[4];
  #pragma unroll
  for (int mt = 0; mt < 4; ++mt) acc[mt] = (f32x4){0.f, 0.f, 0.f, 0.f};

  // per-lane frag offsets (bytes)
  const int xoff = (wid << 10) + (lane << 4);                 // sw*1KB + lane*16B
  const int woff = ((((lane >> 5) ^ 1) << 8) + (((lane >> 4) & 1) << 7) +
                    ((lane & 15) << 3)) * 2;                  // elems->bytes

  STAGE(0, 0);
  __syncthreads();

  #pragma unroll 1
  for (int h = 0; h < 32; ++h) {
    const int buf = h & 1;
    if (h < 31) STAGE(h + 1, buf ^ 1);
    const bf16x8 xv = *reinterpret_cast<const bf16x8*>(Xl + buf * 8192 + xoff);
    const char* wb = Wl + buf * 10240 + woff;
    #pragma unroll
    for (int mt = 0; mt < 4; ++mt) {
      // slot pair for (mt, sw): lanes>=32 -> slot mt+14-2sw, lanes<32 -> +1
      const bf16x8 wf = *reinterpret_cast<const bf16x8*>(wb + ((mt + 14 - (wid << 1)) << 9));
      acc[mt] = __builtin_amdgcn_mfma_f32_16x16x32_bf16(xv, wf, acc[mt], 0, 0, 0);
    }
    __syncthreads();   // next buffer staged; this buffer free for overwrite
  }

  // ---- cross-wave reduction: 8 s-slot partials per output tile.
  // red[sw][mt][elem]: elem = row16*16+col (C/D: col=lane&15, row=(lane>>4)*4+r)
  float* red = reinterpret_cast<float*>(LDSB);   // 32 KB
  #pragma unroll
  for (int mt = 0; mt < 4; ++mt) {
    const int ebase = (wid << 10) + (mt << 8) + (((lane >> 4) << 2) << 4) + (lane & 15);
    #pragma unroll
    for (int r = 0; r < 4; ++r)
      red[ebase + (r << 4)] = acc[mt][r];
  }
  __syncthreads();

  #pragma unroll
  for (int e = tid; e < 1024; e += 512) {
    float s = 0.f;
    #pragma unroll
    for (int sw = 0; sw < 8; ++sw) s += red[(sw << 10) + e];
    const int mt  = e >> 8;
    const int el  = e & 255;
    const int r16 = el >> 4;
    const int c16 = el & 15;
    Out[(b0 * 16 + r16) * DIM + (cg << 6) + (mt << 4) + c16] = s;
  }
}

extern "C" void kernel_launch(void* const* d_in, const int* in_sizes, int n_in,
                              void* d_out, int out_size, void* d_ws, size_t ws_size,
                              hipStream_t stream) {
  const float* X   = (const float*)d_in[0];     // [32, 8192] fp32
  const float* Blk = (const float*)d_in[1];     // [512, 16, 16] fp32
  unsigned short* Xp = (unsigned short*)d_ws;   // 512 KB bf16 repack of X
  unsigned short* Wp = Xp + 262144;             // 256 KB bf16 repack of blocks
  float* Out = (float*)d_out;                   // [32, 8192] fp32

  bcl_prep_kernel<<<dim3(192), dim3(256), 0, stream>>>(X, Blk, Xp, Wp);
  bcl_mono_kernel<<<dim3(256), dim3(512), 0, stream>>>(Xp, Wp, Out);
}